// Round 16
// baseline (228.464 us; speedup 1.0000x reference)
//
#include <hip/hip_runtime.h>
#include <math.h>

#define N_NODES 50000
#define E_RAW   800000
#define E_TOT   850000
#define NEG_SLOPE 0.2f
#define NBC 196        // scan blocks = ceil(50000/256)
#define G1_BLKS 782    // ceil(50000/64)
#define SCAT_BLKS 3321 // ceil(850000/256)
#define GG_BLKS 1563   // ceil(50000/32)

typedef __attribute__((ext_vector_type(8))) short short8;
typedef __attribute__((ext_vector_type(4))) float f32x4;

__device__ __forceinline__ float lrelu(float v) {
    return v >= 0.f ? v : NEG_SLOPE * v;
}
__device__ __forceinline__ unsigned short f2bf(float f) {
    union { float f; unsigned u; } v; v.f = f;
    unsigned r = v.u + 0x7FFF + ((v.u >> 16) & 1);
    return (unsigned short)(r >> 16);
}
__device__ __forceinline__ float bf2f(unsigned short h) {
    union { unsigned u; float f; } v; v.u = ((unsigned)h) << 16;
    return v.f;
}
// h1b position p holds column C1(p) (16x16 transpose, self-inverse)
__device__ __forceinline__ int C1(int p) { return (p & 15) * 16 + (p >> 4); }
// h2b position p holds column C2(p)
__device__ __forceinline__ int C2(int p) { return (p & 3) * 16 + (p >> 2); }

// ---------------------------------------------------------------------------
// prep (weight frags) + histogram, fused.
// ---------------------------------------------------------------------------
__global__ __launch_bounds__(256) void k_prep_hist(
    const int* __restrict__ dst, int* __restrict__ counts,
    const float* __restrict__ W1, const float* __restrict__ W2,
    unsigned short* __restrict__ Wf1, unsigned short* __restrict__ Wf2)
{
    int idx = blockIdx.x * 256 + threadIdx.x;
    if (idx < 8192) {
        int lane = idx & 63, kb = (idx >> 6) & 7, nb = idx >> 9;
        int c = nb * 16 + (lane & 15);
        int k0 = kb * 32 + ((lane >> 4) & 3) * 8;
        short8 pk;
#pragma unroll
        for (int j = 0; j < 8; ++j)
            pk[j] = (short)f2bf(W1[(k0 + j) * 256 + c]);
        *(short8*)&Wf1[idx * 8] = pk;
    } else if (idx < 10240) {
        int i2 = idx - 8192;
        int lane = i2 & 63, kb = (i2 >> 6) & 7, nb = i2 >> 9;
        int c = nb * 16 + (lane & 15);
        int k0 = kb * 32 + ((lane >> 4) & 3) * 8;
        short8 pk;
#pragma unroll
        for (int j = 0; j < 8; ++j)
            pk[j] = (short)f2bf(W2[C1(k0 + j) * 64 + c]);
        *(short8*)&Wf2[i2 * 8] = pk;
    }
    if (idx < E_TOT) {
        int d = (idx < E_RAW) ? dst[idx] : idx - E_RAW;
        atomicAdd(&counts[d], 1);
    }
}

// ---------------------------------------------------------------------------
// scan1: per-block exclusive scan of counts; bsum[b] = block total.
// ---------------------------------------------------------------------------
__global__ __launch_bounds__(256) void k_scan1(
    const int* __restrict__ counts, int* __restrict__ off, int* __restrict__ bsum)
{
    __shared__ int sh[256];
    int t = threadIdx.x, i = blockIdx.x * 256 + t;
    int c = (i < N_NODES) ? counts[i] : 0;
    sh[t] = c; __syncthreads();
    for (int ofs = 1; ofs < 256; ofs <<= 1) {
        int v = (t >= ofs) ? sh[t - ofs] : 0;
        __syncthreads(); sh[t] += v; __syncthreads();
    }
    if (i < N_NODES) off[i] = sh[t] - c;
    if (t == 255) bsum[blockIdx.x] = sh[255];
}

// ---------------------------------------------------------------------------
// scan23 (merged): block b computes base = sum(bsum[0..b-1]) via LDS reduce.
// ---------------------------------------------------------------------------
__global__ __launch_bounds__(256) void k_scan23(
    int* __restrict__ off, const int* __restrict__ bsum)
{
    __shared__ int sh[256];
    int t = threadIdx.x, b = blockIdx.x;
    sh[t] = (t < b) ? bsum[t] : 0;       // b <= 195 < 256
    __syncthreads();
    for (int ofs = 128; ofs > 0; ofs >>= 1) {
        if (t < ofs) sh[t] += sh[t + ofs];
        __syncthreads();
    }
    int base = sh[0];
    int i = b * 256 + t;
    if (i < N_NODES) off[i] += base;
    if (b == 0 && t == 0) off[N_NODES] = E_TOT;
}

// ---------------------------------------------------------------------------
// FUSED gemm1 + scatter. (r15, unchanged)
// ---------------------------------------------------------------------------
__global__ __launch_bounds__(256) void k_gemm1_scatter(
    const float* __restrict__ x, const unsigned short* __restrict__ Wf1,
    const float* __restrict__ att_src, const float* __restrict__ att_dst,
    unsigned short* __restrict__ h1b, float* __restrict__ as1, float* __restrict__ ad1,
    const int* __restrict__ src, const int* __restrict__ dst,
    const int* __restrict__ off, int* __restrict__ counts,
    unsigned short* __restrict__ esrc)
{
    if (blockIdx.x >= G1_BLKS) {
        int e = (blockIdx.x - G1_BLKS) * 256 + threadIdx.x;
        if (e < E_TOT) {
            int s, d;
            if (e < E_RAW) { s = src[e]; d = dst[e]; } else { s = e - E_RAW; d = s; }
            int old = atomicSub(&counts[d], 1);
            esrc[off[d] + old - 1] = (unsigned short)s;
        }
        return;
    }
    __shared__ unsigned short hsx[64 * 264];
    const int t = threadIdx.x;
    const int rbase = blockIdx.x * 64;

#pragma unroll
    for (int it = 0; it < 16; ++it) {
        int idx = it * 1024 + t * 4;
        int row = idx >> 8, col = idx & 255;
        int rA = rbase + row;
        if (rA >= N_NODES) rA = N_NODES - 1;
        float4 v = *(const float4*)&x[rA * 256 + col];
        ushort4 pk;
        pk.x = f2bf(v.x); pk.y = f2bf(v.y); pk.z = f2bf(v.z); pk.w = f2bf(v.w);
        *(ushort4*)&hsx[row * 264 + col] = pk;
    }
    __syncthreads();

    const int lane = t & 63;
    const int w = t >> 6;
    const int q  = lane & 15;
    const int kg = lane >> 4;

    f32x4 acc[4][4];
#pragma unroll
    for (int rg = 0; rg < 4; ++rg)
#pragma unroll
        for (int nb = 0; nb < 4; ++nb) acc[rg][nb] = (f32x4){0.f, 0.f, 0.f, 0.f};

#pragma unroll
    for (int kb = 0; kb < 8; ++kb) {
        short8 b[4];
#pragma unroll
        for (int nb = 0; nb < 4; ++nb)
            b[nb] = *(const short8*)&Wf1[(((w * 4 + nb) * 8 + kb) * 64 + lane) * 8];
#pragma unroll
        for (int rg = 0; rg < 4; ++rg) {
            short8 af = *(const short8*)&hsx[(rg * 16 + q) * 264 + kb * 32 + kg * 8];
#pragma unroll
            for (int nb = 0; nb < 4; ++nb)
                acc[rg][nb] = __builtin_amdgcn_mfma_f32_16x16x32_bf16(af, b[nb], acc[rg][nb], 0, 0, 0);
        }
    }

    float asv[4], adv[4];
#pragma unroll
    for (int nb = 0; nb < 4; ++nb) {
        int col = (w * 4 + nb) * 16 + q;
        asv[nb] = att_src[col];
        adv[nb] = att_dst[col];
    }
#pragma unroll
    for (int rg = 0; rg < 4; ++rg) {
#pragma unroll
        for (int reg = 0; reg < 4; ++reg) {
            int n = rbase + rg * 16 + kg * 4 + reg;
            bool ok = n < N_NODES;
            if (ok) {
                ushort4 pk;
                pk.x = f2bf(acc[rg][0][reg]); pk.y = f2bf(acc[rg][1][reg]);
                pk.z = f2bf(acc[rg][2][reg]); pk.w = f2bf(acc[rg][3][reg]);
                *(ushort4*)&h1b[n * 256 + q * 16 + w * 4] = pk;
            }
            float s = acc[rg][0][reg]*asv[0] + acc[rg][1][reg]*asv[1]
                    + acc[rg][2][reg]*asv[2] + acc[rg][3][reg]*asv[3];
            float d = acc[rg][0][reg]*adv[0] + acc[rg][1][reg]*adv[1]
                    + acc[rg][2][reg]*adv[2] + acc[rg][3][reg]*adv[3];
#pragma unroll
            for (int ofs = 1; ofs < 16; ofs <<= 1) {
                s += __shfl_xor(s, ofs);
                d += __shfl_xor(d, ofs);
            }
            if (ok && q == 0) {
                as1[n * 4 + w] = s;
                ad1[n * 4 + w] = d;
            }
        }
    }
}

// ---------------------------------------------------------------------------
// FUSED gather1 + gemm2 + att2-dots. NOW 512 threads, 32 dst/block
// (1563 blocks): phase-1 imbalance averages over 8 waves; phase-2 reuses
// each Wf2 frag across 2 row-halves. Wave w: phase1 dsts w*4..+3; phase2
// col-slice cg=w&3, row-half rh=w>>2.
// ---------------------------------------------------------------------------
__global__ __launch_bounds__(512) void k_gat1g2(
    const unsigned short* __restrict__ esrc, const int* __restrict__ off,
    const float* __restrict__ as1, const float* __restrict__ ad1,
    const unsigned short* __restrict__ h1b, const float* __restrict__ b1,
    const unsigned short* __restrict__ Wf2,
    const float* __restrict__ att_src2, const float* __restrict__ att_dst2,
    unsigned short* __restrict__ h2b, float* __restrict__ as2, float* __restrict__ ad2)
{
    __shared__ unsigned short hs[32][264];
    __shared__ float ss[32][4], sd[32][4];
    const int t = threadIdx.x;
    const int w = t >> 6;                       // 0..7
    const int lane = t & 63;
    const int d0 = blockIdx.x * 32;
    const int head = lane & 3;

    // ---- phase 1: gather (inline-weight body), 4 dsts per wave ----
    for (int r = 0; r < 4; ++r) {
        const int ld = w * 4 + r;
        const int d = d0 + ld;
        if (d >= N_NODES) {
            *(ushort4*)&hs[ld][lane * 4] = make_ushort4(0, 0, 0, 0);
            continue;
        }
        const float adv = ad1[d * 4 + head];
        const int e0 = off[d], e1 = off[d + 1];
        float4 acc = make_float4(0.f, 0.f, 0.f, 0.f);
        float dn = 0.f;
        int e = e0;
        for (; e + 3 < e1; e += 4) {
            int s0 = esrc[e], s1 = esrc[e + 1], s2 = esrc[e + 2], s3 = esrc[e + 3];
            float w0 = __expf(lrelu(as1[s0 * 4 + head] + adv));
            float w1 = __expf(lrelu(as1[s1 * 4 + head] + adv));
            float w2 = __expf(lrelu(as1[s2 * 4 + head] + adv));
            float w3 = __expf(lrelu(as1[s3 * 4 + head] + adv));
            ushort4 u0 = *(const ushort4*)&h1b[s0 * 256 + lane * 4];
            ushort4 u1 = *(const ushort4*)&h1b[s1 * 256 + lane * 4];
            ushort4 u2 = *(const ushort4*)&h1b[s2 * 256 + lane * 4];
            ushort4 u3 = *(const ushort4*)&h1b[s3 * 256 + lane * 4];
            dn += (w0 + w1) + (w2 + w3);
            acc.x = fmaf(w0, bf2f(u0.x), fmaf(w1, bf2f(u1.x), fmaf(w2, bf2f(u2.x), fmaf(w3, bf2f(u3.x), acc.x))));
            acc.y = fmaf(w0, bf2f(u0.y), fmaf(w1, bf2f(u1.y), fmaf(w2, bf2f(u2.y), fmaf(w3, bf2f(u3.y), acc.y))));
            acc.z = fmaf(w0, bf2f(u0.z), fmaf(w1, bf2f(u1.z), fmaf(w2, bf2f(u2.z), fmaf(w3, bf2f(u3.z), acc.z))));
            acc.w = fmaf(w0, bf2f(u0.w), fmaf(w1, bf2f(u1.w), fmaf(w2, bf2f(u2.w), fmaf(w3, bf2f(u3.w), acc.w))));
        }
        for (; e < e1; ++e) {
            int s0 = esrc[e];
            float w0 = __expf(lrelu(as1[s0 * 4 + head] + adv));
            ushort4 u0 = *(const ushort4*)&h1b[s0 * 256 + lane * 4];
            dn += w0;
            acc.x = fmaf(w0, bf2f(u0.x), acc.x);
            acc.y = fmaf(w0, bf2f(u0.y), acc.y);
            acc.z = fmaf(w0, bf2f(u0.z), acc.z);
            acc.w = fmaf(w0, bf2f(u0.w), acc.w);
        }
        const float inv = 1.f / (dn + 1e-16f);
        float o[4] = {acc.x, acc.y, acc.z, acc.w};
        ushort4 pk;
        unsigned short* pko = (unsigned short*)&pk;
#pragma unroll
        for (int i = 0; i < 4; ++i) {
            float v = o[i] * inv + b1[C1(lane * 4 + i)];
            v = v > 0.f ? v : expm1f(v);
            pko[i] = f2bf(v);
        }
        *(ushort4*)&hs[ld][lane * 4] = pk;
    }
    __syncthreads();

    // ---- phase 2: gemm2; wave w = (col-slice cg, row-half rh) ----
    const int q  = lane & 15;
    const int kg = lane >> 4;
    const int cg = w & 3;
    const int rh = w >> 2;
    f32x4 acc2 = (f32x4){0.f, 0.f, 0.f, 0.f};
#pragma unroll
    for (int kb = 0; kb < 8; ++kb) {
        short8 af = *(const short8*)&hs[rh * 16 + q][kb * 32 + kg * 8];
        short8 bf = *(const short8*)&Wf2[((cg * 8 + kb) * 64 + lane) * 8];
        acc2 = __builtin_amdgcn_mfma_f32_16x16x32_bf16(af, bf, acc2, 0, 0, 0);
    }
    const float asv = att_src2[cg * 16 + q];
    const float adv = att_dst2[cg * 16 + q];
#pragma unroll
    for (int reg = 0; reg < 4; ++reg) {
        int row = rh * 16 + kg * 4 + reg;
        int n = d0 + row;
        bool ok = n < N_NODES;
        if (ok) h2b[n * 64 + q * 4 + cg] = f2bf(acc2[reg]);  // C2-perm: pos q*4+cg = col cg*16+q
        float s = acc2[reg] * asv;
        float d = acc2[reg] * adv;
#pragma unroll
        for (int ofs = 1; ofs < 16; ofs <<= 1) {
            s += __shfl_xor(s, ofs);
            d += __shfl_xor(d, ofs);
        }
        if (q == 0) { ss[row][cg] = s; sd[row][cg] = d; }
    }
    __syncthreads();
    if (t < 32) {
        int n = d0 + t;
        if (n < N_NODES) {
            as2[n] = (ss[t][0] + ss[t][1]) + (ss[t][2] + ss[t][3]);
            ad2[n] = (sd[t][0] + sd[t][1]) + (sd[t][2] + sd[t][3]);
        }
    }
}

// ---------------------------------------------------------------------------
// gather2: 4 dst per wave (16-lane group owns ushort4 = 128B row), 4x unroll,
// inline exp. Writes d_out (un-permuting C2). (r12, unchanged)
// ---------------------------------------------------------------------------
__global__ __launch_bounds__(256) void k_gather2(
    const unsigned short* __restrict__ esrc, const int* __restrict__ off,
    const float* __restrict__ as2, const float* __restrict__ ad2,
    const unsigned short* __restrict__ h2b, const float* __restrict__ b2,
    float* __restrict__ out)
{
    const int t = threadIdx.x;
    const int w = t >> 6;
    const int lane = t & 63;
    const int g  = lane >> 4;
    const int j2 = lane & 15;
    const int d = blockIdx.x * 16 + w * 4 + g;      // 3125*16 = 50000 exact
    const float adv = ad2[d];
    const int e0 = off[d], e1 = off[d + 1];
    const unsigned short* hb = h2b + j2 * 4;

    float acc[4] = {0.f, 0.f, 0.f, 0.f};
    float dn = 0.f;
    int e = e0;
    for (; e + 3 < e1; e += 4) {
        int s0 = esrc[e], s1 = esrc[e + 1], s2 = esrc[e + 2], s3 = esrc[e + 3];
        float w0 = __expf(lrelu(as2[s0] + adv));
        float w1 = __expf(lrelu(as2[s1] + adv));
        float w2 = __expf(lrelu(as2[s2] + adv));
        float w3 = __expf(lrelu(as2[s3] + adv));
        ushort4 u0 = *(const ushort4*)(hb + s0 * 64);
        ushort4 u1 = *(const ushort4*)(hb + s1 * 64);
        ushort4 u2 = *(const ushort4*)(hb + s2 * 64);
        ushort4 u3 = *(const ushort4*)(hb + s3 * 64);
        dn += (w0 + w1) + (w2 + w3);
        acc[0] = fmaf(w0, bf2f(u0.x), fmaf(w1, bf2f(u1.x), fmaf(w2, bf2f(u2.x), fmaf(w3, bf2f(u3.x), acc[0]))));
        acc[1] = fmaf(w0, bf2f(u0.y), fmaf(w1, bf2f(u1.y), fmaf(w2, bf2f(u2.y), fmaf(w3, bf2f(u3.y), acc[1]))));
        acc[2] = fmaf(w0, bf2f(u0.z), fmaf(w1, bf2f(u1.z), fmaf(w2, bf2f(u2.z), fmaf(w3, bf2f(u3.z), acc[2]))));
        acc[3] = fmaf(w0, bf2f(u0.w), fmaf(w1, bf2f(u1.w), fmaf(w2, bf2f(u2.w), fmaf(w3, bf2f(u3.w), acc[3]))));
    }
    for (; e < e1; ++e) {
        int s0 = esrc[e];
        float w0 = __expf(lrelu(as2[s0] + adv));
        ushort4 u0 = *(const ushort4*)(hb + s0 * 64);
        dn += w0;
        acc[0] = fmaf(w0, bf2f(u0.x), acc[0]);
        acc[1] = fmaf(w0, bf2f(u0.y), acc[1]);
        acc[2] = fmaf(w0, bf2f(u0.z), acc[2]);
        acc[3] = fmaf(w0, bf2f(u0.w), acc[3]);
    }
    const float inv = 1.f / (dn + 1e-16f);
#pragma unroll
    for (int i = 0; i < 4; ++i) {
        int col = i * 16 + j2;                      // C2(j2*4+i)
        out[d * 64 + col] = acc[i] * inv + b2[col];
    }
}

// ---------------------------------------------------------------------------
// Workspace layout (bytes), total ~36.3 MB (r14 layout, unchanged):
//   counts @ 0            200,000  [zeroed; consumed as cursor by scatter]
//   off    @ 200,000      200,004
//   bsum   @ 400,032      800
//   as1    @ 400,896      800,000
//   ad1    @ 1,200,896    800,000
//   as2    @ 2,000,896    200,000
//   ad2    @ 2,200,896    200,000
//   esrc   @ 2,400,896    1,700,000  uint16
//   Wf1    @ 4,100,896    131,072
//   Wf2    @ 4,231,968    32,768
//   h1b    @ 4,264,736    25,600,000 bf16 C1-perm
//   h2b    @ 29,864,736   6,400,000  bf16 C2-perm
// ---------------------------------------------------------------------------
extern "C" void kernel_launch(void* const* d_in, const int* in_sizes, int n_in,
                              void* d_out, int out_size, void* d_ws, size_t ws_size,
                              hipStream_t stream)
{
    const float* x        = (const float*)d_in[0];
    const int*   ei       = (const int*)d_in[1];
    const float* W1       = (const float*)d_in[2];
    const float* att_src1 = (const float*)d_in[3];
    const float* att_dst1 = (const float*)d_in[4];
    const float* b1       = (const float*)d_in[5];
    const float* W2       = (const float*)d_in[6];
    const float* att_src2 = (const float*)d_in[7];
    const float* att_dst2 = (const float*)d_in[8];
    const float* b2       = (const float*)d_in[9];
    const int* src = ei;
    const int* dst = ei + E_RAW;
    float* out = (float*)d_out;

    char* ws = (char*)d_ws;
    int*            counts = (int*)(ws + 0);
    int*            off    = (int*)(ws + 200000);
    int*            bsum   = (int*)(ws + 400032);
    float*          as1    = (float*)(ws + 400896);
    float*          ad1    = (float*)(ws + 1200896);
    float*          as2    = (float*)(ws + 2000896);
    float*          ad2    = (float*)(ws + 2200896);
    unsigned short* esrc   = (unsigned short*)(ws + 2400896);
    unsigned short* Wf1    = (unsigned short*)(ws + 4100896);
    unsigned short* Wf2    = (unsigned short*)(ws + 4231968);
    unsigned short* h1b    = (unsigned short*)(ws + 4264736);
    unsigned short* h2b    = (unsigned short*)(ws + 29864736);

    hipMemsetAsync(counts, 0, 200000, stream);

    const int EB = (E_TOT + 255) / 256;
    k_prep_hist<<<EB, 256, 0, stream>>>(dst, counts, W1, W2, Wf1, Wf2);
    k_scan1  <<<NBC, 256, 0, stream>>>(counts, off, bsum);
    k_scan23 <<<NBC, 256, 0, stream>>>(off, bsum);
    k_gemm1_scatter<<<G1_BLKS + SCAT_BLKS, 256, 0, stream>>>(
        x, Wf1, att_src1, att_dst1, h1b, as1, ad1,
        src, dst, off, counts, esrc);
    k_gat1g2 <<<GG_BLKS, 512, 0, stream>>>(esrc, off, as1, ad1, h1b, b1, Wf2,
                                           att_src2, att_dst2, h2b, as2, ad2);
    k_gather2<<<3125, 256, 0, stream>>>(esrc, off, as2, ad2, h2b, b2, out);
}

// Round 17
// 217.985 us; speedup vs baseline: 1.0481x; 1.0481x over previous
//
#include <hip/hip_runtime.h>
#include <math.h>

#define N_NODES 50000
#define E_RAW   800000
#define E_TOT   850000
#define NEG_SLOPE 0.2f
#define NBC 196        // scan blocks = ceil(50000/256)
#define G1_BLKS 782    // ceil(50000/64)
#define SCAT_BLKS 3321 // ceil(850000/256)

typedef __attribute__((ext_vector_type(8))) short short8;
typedef __attribute__((ext_vector_type(4))) float f32x4;

__device__ __forceinline__ float lrelu(float v) {
    return v >= 0.f ? v : NEG_SLOPE * v;
}
__device__ __forceinline__ unsigned short f2bf(float f) {
    union { float f; unsigned u; } v; v.f = f;
    unsigned r = v.u + 0x7FFF + ((v.u >> 16) & 1);
    return (unsigned short)(r >> 16);
}
__device__ __forceinline__ float bf2f(unsigned short h) {
    union { unsigned u; float f; } v; v.u = ((unsigned)h) << 16;
    return v.f;
}
// h1b position p holds column C1(p) (16x16 transpose, self-inverse)
__device__ __forceinline__ int C1(int p) { return (p & 15) * 16 + (p >> 4); }
// h2b position p holds column C2(p)
__device__ __forceinline__ int C2(int p) { return (p & 3) * 16 + (p >> 2); }

// ---------------------------------------------------------------------------
// prep (weight frags) + histogram, fused.
// ---------------------------------------------------------------------------
__global__ __launch_bounds__(256) void k_prep_hist(
    const int* __restrict__ dst, int* __restrict__ counts,
    const float* __restrict__ W1, const float* __restrict__ W2,
    unsigned short* __restrict__ Wf1, unsigned short* __restrict__ Wf2)
{
    int idx = blockIdx.x * 256 + threadIdx.x;
    if (idx < 8192) {
        int lane = idx & 63, kb = (idx >> 6) & 7, nb = idx >> 9;
        int c = nb * 16 + (lane & 15);
        int k0 = kb * 32 + ((lane >> 4) & 3) * 8;
        short8 pk;
#pragma unroll
        for (int j = 0; j < 8; ++j)
            pk[j] = (short)f2bf(W1[(k0 + j) * 256 + c]);
        *(short8*)&Wf1[idx * 8] = pk;
    } else if (idx < 10240) {
        int i2 = idx - 8192;
        int lane = i2 & 63, kb = (i2 >> 6) & 7, nb = i2 >> 9;
        int c = nb * 16 + (lane & 15);
        int k0 = kb * 32 + ((lane >> 4) & 3) * 8;
        short8 pk;
#pragma unroll
        for (int j = 0; j < 8; ++j)
            pk[j] = (short)f2bf(W2[C1(k0 + j) * 64 + c]);
        *(short8*)&Wf2[i2 * 8] = pk;
    }
    if (idx < E_TOT) {
        int d = (idx < E_RAW) ? dst[idx] : idx - E_RAW;
        atomicAdd(&counts[d], 1);
    }
}

// ---------------------------------------------------------------------------
// scan1: per-block exclusive scan of counts; bsum[b] = block total.
// ---------------------------------------------------------------------------
__global__ __launch_bounds__(256) void k_scan1(
    const int* __restrict__ counts, int* __restrict__ off, int* __restrict__ bsum)
{
    __shared__ int sh[256];
    int t = threadIdx.x, i = blockIdx.x * 256 + t;
    int c = (i < N_NODES) ? counts[i] : 0;
    sh[t] = c; __syncthreads();
    for (int ofs = 1; ofs < 256; ofs <<= 1) {
        int v = (t >= ofs) ? sh[t - ofs] : 0;
        __syncthreads(); sh[t] += v; __syncthreads();
    }
    if (i < N_NODES) off[i] = sh[t] - c;
    if (t == 255) bsum[blockIdx.x] = sh[255];
}

// ---------------------------------------------------------------------------
// scan23 (merged): block b computes base = sum(bsum[0..b-1]) via LDS reduce.
// ---------------------------------------------------------------------------
__global__ __launch_bounds__(256) void k_scan23(
    int* __restrict__ off, const int* __restrict__ bsum)
{
    __shared__ int sh[256];
    int t = threadIdx.x, b = blockIdx.x;
    sh[t] = (t < b) ? bsum[t] : 0;       // b <= 195 < 256
    __syncthreads();
    for (int ofs = 128; ofs > 0; ofs >>= 1) {
        if (t < ofs) sh[t] += sh[t + ofs];
        __syncthreads();
    }
    int base = sh[0];
    int i = b * 256 + t;
    if (i < N_NODES) off[i] += base;
    if (b == 0 && t == 0) off[N_NODES] = E_TOT;
}

// ---------------------------------------------------------------------------
// FUSED gemm1 + scatter. (r15, unchanged)
// ---------------------------------------------------------------------------
__global__ __launch_bounds__(256) void k_gemm1_scatter(
    const float* __restrict__ x, const unsigned short* __restrict__ Wf1,
    const float* __restrict__ att_src, const float* __restrict__ att_dst,
    unsigned short* __restrict__ h1b, float* __restrict__ as1, float* __restrict__ ad1,
    const int* __restrict__ src, const int* __restrict__ dst,
    const int* __restrict__ off, int* __restrict__ counts,
    unsigned short* __restrict__ esrc)
{
    if (blockIdx.x >= G1_BLKS) {
        int e = (blockIdx.x - G1_BLKS) * 256 + threadIdx.x;
        if (e < E_TOT) {
            int s, d;
            if (e < E_RAW) { s = src[e]; d = dst[e]; } else { s = e - E_RAW; d = s; }
            int old = atomicSub(&counts[d], 1);
            esrc[off[d] + old - 1] = (unsigned short)s;
        }
        return;
    }
    __shared__ unsigned short hsx[64 * 264];
    const int t = threadIdx.x;
    const int rbase = blockIdx.x * 64;

#pragma unroll
    for (int it = 0; it < 16; ++it) {
        int idx = it * 1024 + t * 4;
        int row = idx >> 8, col = idx & 255;
        int rA = rbase + row;
        if (rA >= N_NODES) rA = N_NODES - 1;
        float4 v = *(const float4*)&x[rA * 256 + col];
        ushort4 pk;
        pk.x = f2bf(v.x); pk.y = f2bf(v.y); pk.z = f2bf(v.z); pk.w = f2bf(v.w);
        *(ushort4*)&hsx[row * 264 + col] = pk;
    }
    __syncthreads();

    const int lane = t & 63;
    const int w = t >> 6;
    const int q  = lane & 15;
    const int kg = lane >> 4;

    f32x4 acc[4][4];
#pragma unroll
    for (int rg = 0; rg < 4; ++rg)
#pragma unroll
        for (int nb = 0; nb < 4; ++nb) acc[rg][nb] = (f32x4){0.f, 0.f, 0.f, 0.f};

#pragma unroll
    for (int kb = 0; kb < 8; ++kb) {
        short8 b[4];
#pragma unroll
        for (int nb = 0; nb < 4; ++nb)
            b[nb] = *(const short8*)&Wf1[(((w * 4 + nb) * 8 + kb) * 64 + lane) * 8];
#pragma unroll
        for (int rg = 0; rg < 4; ++rg) {
            short8 af = *(const short8*)&hsx[(rg * 16 + q) * 264 + kb * 32 + kg * 8];
#pragma unroll
            for (int nb = 0; nb < 4; ++nb)
                acc[rg][nb] = __builtin_amdgcn_mfma_f32_16x16x32_bf16(af, b[nb], acc[rg][nb], 0, 0, 0);
        }
    }

    float asv[4], adv[4];
#pragma unroll
    for (int nb = 0; nb < 4; ++nb) {
        int col = (w * 4 + nb) * 16 + q;
        asv[nb] = att_src[col];
        adv[nb] = att_dst[col];
    }
#pragma unroll
    for (int rg = 0; rg < 4; ++rg) {
#pragma unroll
        for (int reg = 0; reg < 4; ++reg) {
            int n = rbase + rg * 16 + kg * 4 + reg;
            bool ok = n < N_NODES;
            if (ok) {
                ushort4 pk;
                pk.x = f2bf(acc[rg][0][reg]); pk.y = f2bf(acc[rg][1][reg]);
                pk.z = f2bf(acc[rg][2][reg]); pk.w = f2bf(acc[rg][3][reg]);
                *(ushort4*)&h1b[n * 256 + q * 16 + w * 4] = pk;
            }
            float s = acc[rg][0][reg]*asv[0] + acc[rg][1][reg]*asv[1]
                    + acc[rg][2][reg]*asv[2] + acc[rg][3][reg]*asv[3];
            float d = acc[rg][0][reg]*adv[0] + acc[rg][1][reg]*adv[1]
                    + acc[rg][2][reg]*adv[2] + acc[rg][3][reg]*adv[3];
#pragma unroll
            for (int ofs = 1; ofs < 16; ofs <<= 1) {
                s += __shfl_xor(s, ofs);
                d += __shfl_xor(d, ofs);
            }
            if (ok && q == 0) {
                as1[n * 4 + w] = s;
                ad1[n * 4 + w] = d;
            }
        }
    }
}

// ---------------------------------------------------------------------------
// FUSED gather1 + gemm2 + att2-dots. Block = 16 dst, 256 threads (r15 form —
// the 512-thread/32-dst variant regressed 84->91 us in r16: max-of-8 barrier
// wait + coarser scheduling granularity).
// ---------------------------------------------------------------------------
__global__ __launch_bounds__(256) void k_gat1g2(
    const unsigned short* __restrict__ esrc, const int* __restrict__ off,
    const float* __restrict__ as1, const float* __restrict__ ad1,
    const unsigned short* __restrict__ h1b, const float* __restrict__ b1,
    const unsigned short* __restrict__ Wf2,
    const float* __restrict__ att_src2, const float* __restrict__ att_dst2,
    unsigned short* __restrict__ h2b, float* __restrict__ as2, float* __restrict__ ad2)
{
    __shared__ unsigned short hs[16][264];
    __shared__ float ss[16][4], sd[16][4];
    const int t = threadIdx.x;
    const int w = t >> 6;
    const int lane = t & 63;
    const int d0 = blockIdx.x * 16;
    const int head = lane & 3;

    // ---- phase 1: gather (inline-weight body), 4 dsts per wave ----
    for (int r = 0; r < 4; ++r) {
        const int ld = w * 4 + r;
        const int d = d0 + ld;
        const float adv = ad1[d * 4 + head];
        const int e0 = off[d], e1 = off[d + 1];
        float4 acc = make_float4(0.f, 0.f, 0.f, 0.f);
        float dn = 0.f;
        int e = e0;
        for (; e + 3 < e1; e += 4) {
            int s0 = esrc[e], s1 = esrc[e + 1], s2 = esrc[e + 2], s3 = esrc[e + 3];
            float w0 = __expf(lrelu(as1[s0 * 4 + head] + adv));
            float w1 = __expf(lrelu(as1[s1 * 4 + head] + adv));
            float w2 = __expf(lrelu(as1[s2 * 4 + head] + adv));
            float w3 = __expf(lrelu(as1[s3 * 4 + head] + adv));
            ushort4 u0 = *(const ushort4*)&h1b[s0 * 256 + lane * 4];
            ushort4 u1 = *(const ushort4*)&h1b[s1 * 256 + lane * 4];
            ushort4 u2 = *(const ushort4*)&h1b[s2 * 256 + lane * 4];
            ushort4 u3 = *(const ushort4*)&h1b[s3 * 256 + lane * 4];
            dn += (w0 + w1) + (w2 + w3);
            acc.x = fmaf(w0, bf2f(u0.x), fmaf(w1, bf2f(u1.x), fmaf(w2, bf2f(u2.x), fmaf(w3, bf2f(u3.x), acc.x))));
            acc.y = fmaf(w0, bf2f(u0.y), fmaf(w1, bf2f(u1.y), fmaf(w2, bf2f(u2.y), fmaf(w3, bf2f(u3.y), acc.y))));
            acc.z = fmaf(w0, bf2f(u0.z), fmaf(w1, bf2f(u1.z), fmaf(w2, bf2f(u2.z), fmaf(w3, bf2f(u3.z), acc.z))));
            acc.w = fmaf(w0, bf2f(u0.w), fmaf(w1, bf2f(u1.w), fmaf(w2, bf2f(u2.w), fmaf(w3, bf2f(u3.w), acc.w))));
        }
        for (; e < e1; ++e) {
            int s0 = esrc[e];
            float w0 = __expf(lrelu(as1[s0 * 4 + head] + adv));
            ushort4 u0 = *(const ushort4*)&h1b[s0 * 256 + lane * 4];
            dn += w0;
            acc.x = fmaf(w0, bf2f(u0.x), acc.x);
            acc.y = fmaf(w0, bf2f(u0.y), acc.y);
            acc.z = fmaf(w0, bf2f(u0.z), acc.z);
            acc.w = fmaf(w0, bf2f(u0.w), acc.w);
        }
        const float inv = 1.f / (dn + 1e-16f);
        float o[4] = {acc.x, acc.y, acc.z, acc.w};
        ushort4 pk;
        unsigned short* pko = (unsigned short*)&pk;
#pragma unroll
        for (int i = 0; i < 4; ++i) {
            float v = o[i] * inv + b1[C1(lane * 4 + i)];
            v = v > 0.f ? v : expm1f(v);
            pko[i] = f2bf(v);
        }
        *(ushort4*)&hs[ld][lane * 4] = pk;
    }
    __syncthreads();

    // ---- phase 2: gemm2 cols w*16..+15 for the 16 rows ----
    const int q  = lane & 15;
    const int kg = lane >> 4;
    f32x4 acc2 = (f32x4){0.f, 0.f, 0.f, 0.f};
#pragma unroll
    for (int kb = 0; kb < 8; ++kb) {
        short8 af = *(const short8*)&hs[q][kb * 32 + kg * 8];
        short8 bf = *(const short8*)&Wf2[((w * 8 + kb) * 64 + lane) * 8];
        acc2 = __builtin_amdgcn_mfma_f32_16x16x32_bf16(af, bf, acc2, 0, 0, 0);
    }
    const float asv = att_src2[w * 16 + q];
    const float adv = att_dst2[w * 16 + q];
#pragma unroll
    for (int reg = 0; reg < 4; ++reg) {
        int row = kg * 4 + reg;
        int n = d0 + row;
        h2b[n * 64 + q * 4 + w] = f2bf(acc2[reg]);   // C2-perm: pos q*4+w = col w*16+q
        float s = acc2[reg] * asv;
        float d = acc2[reg] * adv;
#pragma unroll
        for (int ofs = 1; ofs < 16; ofs <<= 1) {
            s += __shfl_xor(s, ofs);
            d += __shfl_xor(d, ofs);
        }
        if (q == 0) { ss[row][w] = s; sd[row][w] = d; }
    }
    __syncthreads();
    if (t < 16) {
        as2[d0 + t] = (ss[t][0] + ss[t][1]) + (ss[t][2] + ss[t][3]);
        ad2[d0 + t] = (sd[t][0] + sd[t][1]) + (sd[t][2] + sd[t][3]);
    }
}

// ---------------------------------------------------------------------------
// gather2: 4 dst per wave (16-lane group owns ushort4 = 128B row), 4x unroll,
// inline exp. Writes d_out (un-permuting C2). (r12, unchanged)
// ---------------------------------------------------------------------------
__global__ __launch_bounds__(256) void k_gather2(
    const unsigned short* __restrict__ esrc, const int* __restrict__ off,
    const float* __restrict__ as2, const float* __restrict__ ad2,
    const unsigned short* __restrict__ h2b, const float* __restrict__ b2,
    float* __restrict__ out)
{
    const int t = threadIdx.x;
    const int w = t >> 6;
    const int lane = t & 63;
    const int g  = lane >> 4;
    const int j2 = lane & 15;
    const int d = blockIdx.x * 16 + w * 4 + g;      // 3125*16 = 50000 exact
    const float adv = ad2[d];
    const int e0 = off[d], e1 = off[d + 1];
    const unsigned short* hb = h2b + j2 * 4;

    float acc[4] = {0.f, 0.f, 0.f, 0.f};
    float dn = 0.f;
    int e = e0;
    for (; e + 3 < e1; e += 4) {
        int s0 = esrc[e], s1 = esrc[e + 1], s2 = esrc[e + 2], s3 = esrc[e + 3];
        float w0 = __expf(lrelu(as2[s0] + adv));
        float w1 = __expf(lrelu(as2[s1] + adv));
        float w2 = __expf(lrelu(as2[s2] + adv));
        float w3 = __expf(lrelu(as2[s3] + adv));
        ushort4 u0 = *(const ushort4*)(hb + s0 * 64);
        ushort4 u1 = *(const ushort4*)(hb + s1 * 64);
        ushort4 u2 = *(const ushort4*)(hb + s2 * 64);
        ushort4 u3 = *(const ushort4*)(hb + s3 * 64);
        dn += (w0 + w1) + (w2 + w3);
        acc[0] = fmaf(w0, bf2f(u0.x), fmaf(w1, bf2f(u1.x), fmaf(w2, bf2f(u2.x), fmaf(w3, bf2f(u3.x), acc[0]))));
        acc[1] = fmaf(w0, bf2f(u0.y), fmaf(w1, bf2f(u1.y), fmaf(w2, bf2f(u2.y), fmaf(w3, bf2f(u3.y), acc[1]))));
        acc[2] = fmaf(w0, bf2f(u0.z), fmaf(w1, bf2f(u1.z), fmaf(w2, bf2f(u2.z), fmaf(w3, bf2f(u3.z), acc[2]))));
        acc[3] = fmaf(w0, bf2f(u0.w), fmaf(w1, bf2f(u1.w), fmaf(w2, bf2f(u2.w), fmaf(w3, bf2f(u3.w), acc[3]))));
    }
    for (; e < e1; ++e) {
        int s0 = esrc[e];
        float w0 = __expf(lrelu(as2[s0] + adv));
        ushort4 u0 = *(const ushort4*)(hb + s0 * 64);
        dn += w0;
        acc[0] = fmaf(w0, bf2f(u0.x), acc[0]);
        acc[1] = fmaf(w0, bf2f(u0.y), acc[1]);
        acc[2] = fmaf(w0, bf2f(u0.z), acc[2]);
        acc[3] = fmaf(w0, bf2f(u0.w), acc[3]);
    }
    const float inv = 1.f / (dn + 1e-16f);
#pragma unroll
    for (int i = 0; i < 4; ++i) {
        int col = i * 16 + j2;                      // C2(j2*4+i)
        out[d * 64 + col] = acc[i] * inv + b2[col];
    }
}

// ---------------------------------------------------------------------------
// Workspace layout (bytes), total ~36.3 MB (r14 layout, unchanged):
//   counts @ 0            200,000  [zeroed; consumed as cursor by scatter]
//   off    @ 200,000      200,004
//   bsum   @ 400,032      800
//   as1    @ 400,896      800,000
//   ad1    @ 1,200,896    800,000
//   as2    @ 2,000,896    200,000
//   ad2    @ 2,200,896    200,000
//   esrc   @ 2,400,896    1,700,000  uint16
//   Wf1    @ 4,100,896    131,072
//   Wf2    @ 4,231,968    32,768
//   h1b    @ 4,264,736    25,600,000 bf16 C1-perm
//   h2b    @ 29,864,736   6,400,000  bf16 C2-perm
// ---------------------------------------------------------------------------
extern "C" void kernel_launch(void* const* d_in, const int* in_sizes, int n_in,
                              void* d_out, int out_size, void* d_ws, size_t ws_size,
                              hipStream_t stream)
{
    const float* x        = (const float*)d_in[0];
    const int*   ei       = (const int*)d_in[1];
    const float* W1       = (const float*)d_in[2];
    const float* att_src1 = (const float*)d_in[3];
    const float* att_dst1 = (const float*)d_in[4];
    const float* b1       = (const float*)d_in[5];
    const float* W2       = (const float*)d_in[6];
    const float* att_src2 = (const float*)d_in[7];
    const float* att_dst2 = (const float*)d_in[8];
    const float* b2       = (const float*)d_in[9];
    const int* src = ei;
    const int* dst = ei + E_RAW;
    float* out = (float*)d_out;

    char* ws = (char*)d_ws;
    int*            counts = (int*)(ws + 0);
    int*            off    = (int*)(ws + 200000);
    int*            bsum   = (int*)(ws + 400032);
    float*          as1    = (float*)(ws + 400896);
    float*          ad1    = (float*)(ws + 1200896);
    float*          as2    = (float*)(ws + 2000896);
    float*          ad2    = (float*)(ws + 2200896);
    unsigned short* esrc   = (unsigned short*)(ws + 2400896);
    unsigned short* Wf1    = (unsigned short*)(ws + 4100896);
    unsigned short* Wf2    = (unsigned short*)(ws + 4231968);
    unsigned short* h1b    = (unsigned short*)(ws + 4264736);
    unsigned short* h2b    = (unsigned short*)(ws + 29864736);

    hipMemsetAsync(counts, 0, 200000, stream);

    const int EB = (E_TOT + 255) / 256;
    k_prep_hist<<<EB, 256, 0, stream>>>(dst, counts, W1, W2, Wf1, Wf2);
    k_scan1  <<<NBC, 256, 0, stream>>>(counts, off, bsum);
    k_scan23 <<<NBC, 256, 0, stream>>>(off, bsum);
    k_gemm1_scatter<<<G1_BLKS + SCAT_BLKS, 256, 0, stream>>>(
        x, Wf1, att_src1, att_dst1, h1b, as1, ad1,
        src, dst, off, counts, esrc);
    k_gat1g2 <<<3125, 256, 0, stream>>>(esrc, off, as1, ad1, h1b, b1, Wf2,
                                        att_src2, att_dst2, h2b, as2, ad2);
    k_gather2<<<3125, 256, 0, stream>>>(esrc, off, as2, ad2, h2b, b2, out);
}